// Round 1
// baseline (3408.236 us; speedup 1.0000x reference)
//
#include <hip/hip_runtime.h>

// ChebNet: 3x ChebConv(K=5) + mean-pool + MLP on MI355X.
// Round 1: correctness-first decomposition. Scatter = per-(edge,feat) atomics.

constexpr int N_NODES  = 50000;
constexpr int N_EDGES  = 1600000;
constexpr int N_GRAPHS = 128;

static inline int cdiv_ll(long long a, int b) { return (int)((a + b - 1) / b); }

__global__ void deg_kernel(const int* __restrict__ src, const int* __restrict__ dst,
                           float* __restrict__ deg) {
    int e = blockIdx.x * blockDim.x + threadIdx.x;
    if (e < N_EDGES) {
        int s = src[e];
        if (s != dst[e]) atomicAdd(&deg[s], 1.0f);
    }
}

__global__ void dinv_kernel(float* __restrict__ deg) {
    int i = blockIdx.x * blockDim.x + threadIdx.x;
    if (i < N_NODES) {
        float d = deg[i];
        deg[i] = d > 0.f ? rsqrtf(d) : 0.f;
    }
}

__global__ void edgew_kernel(const int* __restrict__ src, const int* __restrict__ dst,
                             const float* __restrict__ dinv, float* __restrict__ w) {
    int e = blockIdx.x * blockDim.x + threadIdx.x;
    if (e < N_EDGES) {
        int s = src[e], d = dst[e];
        w[e] = (s != d) ? (-dinv[s] * dinv[d]) : 0.f;
    }
}

// out[dst[e]*F + f] += scale * w[e] * z[src[e]*F + f]
template <int F>
__global__ void scatter_kernel(const int* __restrict__ src, const int* __restrict__ dst,
                               const float* __restrict__ w, const float* __restrict__ z,
                               float* __restrict__ out, float scale) {
    long long tid = (long long)blockIdx.x * blockDim.x + threadIdx.x;
    if (tid < (long long)N_EDGES * F) {
        int e = (int)(tid / F);
        int f = (int)(tid % F);
        float we = w[e] * scale;
        if (we != 0.f) {
            atomicAdd(&out[(long long)dst[e] * F + f], we * z[(long long)src[e] * F + f]);
        }
    }
}

__global__ void copy_neg_kernel(const float* __restrict__ in, float* __restrict__ out, int n) {
    int i = blockIdx.x * blockDim.x + threadIdx.x;
    if (i < n) out[i] = -in[i];
}

// out[n,o] += sum_f Tx[n,f] * W[f,o]
template <int FI, int FO>
__global__ void addmm_kernel(const float* __restrict__ Tx, const float* __restrict__ W,
                             float* __restrict__ out) {
    int tid = blockIdx.x * blockDim.x + threadIdx.x;
    if (tid < N_NODES * FO) {
        int n = tid / FO, o = tid % FO;
        const float* t = Tx + (long long)n * FI;
        float acc = 0.f;
#pragma unroll
        for (int f = 0; f < FI; ++f) acc = fmaf(t[f], W[f * FO + o], acc);
        out[tid] += acc;
    }
}

template <int FO>
__global__ void bias_relu_kernel(const float* __restrict__ in, const float* __restrict__ b,
                                 float* __restrict__ out) {
    int tid = blockIdx.x * blockDim.x + threadIdx.x;
    if (tid < N_NODES * FO) {
        float v = in[tid] + b[tid % FO];
        out[tid] = v > 0.f ? v : 0.f;
    }
}

__global__ void pool_kernel(const float* __restrict__ h, const int* __restrict__ batch,
                            float* __restrict__ pooled, float* __restrict__ cnt) {
    int tid = blockIdx.x * blockDim.x + threadIdx.x;
    if (tid < N_NODES * 64) {
        int n = tid >> 6, f = tid & 63;
        int g = batch[n];
        atomicAdd(&pooled[g * 64 + f], h[tid]);
        if (f == 0) atomicAdd(&cnt[g], 1.0f);
    }
}

__global__ void fc_kernel(const float* __restrict__ pooled, const float* __restrict__ cnt,
                          const float* __restrict__ w1, const float* __restrict__ b1,
                          const float* __restrict__ w2, const float* __restrict__ b2,
                          float* __restrict__ out) {
    int g = blockIdx.x;
    int t = threadIdx.x;  // 32 threads
    __shared__ float hid[32];
    float c = fmaxf(cnt[g], 1.0f);
    float acc = b1[t];
    for (int f = 0; f < 64; ++f) acc = fmaf(pooled[g * 64 + f] / c, w1[f * 32 + t], acc);
    hid[t] = fmaxf(acc, 0.f);
    __syncthreads();
    if (t == 0) {
        float acc2 = b2[0];
        for (int o = 0; o < 32; ++o) acc2 = fmaf(hid[o], w2[o], acc2);
        out[g] = acc2;
    }
}

template <int FI, int FO>
static void run_cheb(const int* src, const int* dst, const float* w,
                     const float* X, float* T1, float* T2, float* T3,
                     float* OUT, const float* Wk, const float* b, float* H,
                     hipStream_t stream) {
    const int TPB = 256;
    size_t nfi_bytes = (size_t)N_NODES * FI * sizeof(float);
    long long scat_threads = (long long)N_EDGES * FI;
    int mm_threads = N_NODES * FO;

    // Tx1 = L(X) into T1
    hipMemsetAsync(T1, 0, nfi_bytes, stream);
    hipLaunchKernelGGL((scatter_kernel<FI>), dim3(cdiv_ll(scat_threads, TPB)), dim3(TPB), 0,
                       stream, src, dst, w, X, T1, 1.0f);
    // OUT = X@W0 + T1@W1
    hipMemsetAsync(OUT, 0, (size_t)N_NODES * FO * sizeof(float), stream);
    hipLaunchKernelGGL((addmm_kernel<FI, FO>), dim3(cdiv_ll(mm_threads, TPB)), dim3(TPB), 0,
                       stream, X, Wk, OUT);
    hipLaunchKernelGGL((addmm_kernel<FI, FO>), dim3(cdiv_ll(mm_threads, TPB)), dim3(TPB), 0,
                       stream, T1, Wk + FI * FO, OUT);

    const float* Tx0 = X;
    const float* Tx1 = T1;
    float* nxt[3] = {T2, T3, T1};
    for (int k = 2; k < 5; ++k) {
        float* Tx2 = nxt[k - 2];
        // Tx2 = -Tx0, then Tx2 += 2 * L(Tx1)
        hipLaunchKernelGGL(copy_neg_kernel, dim3(cdiv_ll(N_NODES * FI, TPB)), dim3(TPB), 0,
                           stream, Tx0, Tx2, N_NODES * FI);
        hipLaunchKernelGGL((scatter_kernel<FI>), dim3(cdiv_ll(scat_threads, TPB)), dim3(TPB), 0,
                           stream, src, dst, w, Tx1, Tx2, 2.0f);
        hipLaunchKernelGGL((addmm_kernel<FI, FO>), dim3(cdiv_ll(mm_threads, TPB)), dim3(TPB), 0,
                           stream, Tx2, Wk + (size_t)k * FI * FO, OUT);
        Tx0 = Tx1;
        Tx1 = Tx2;
    }
    hipLaunchKernelGGL((bias_relu_kernel<FO>), dim3(cdiv_ll(N_NODES * FO, TPB)), dim3(TPB), 0,
                       stream, OUT, b, H);
}

extern "C" void kernel_launch(void* const* d_in, const int* in_sizes, int n_in,
                              void* d_out, int out_size, void* d_ws, size_t ws_size,
                              hipStream_t stream) {
    const float* x    = (const float*)d_in[0];
    const int*   ei   = (const int*)d_in[1];
    const int*   batch= (const int*)d_in[2];
    // d_in[3] = num_graphs scalar (128), compiled in as constant
    const float* W1   = (const float*)d_in[4];
    const float* b1   = (const float*)d_in[5];
    const float* W2   = (const float*)d_in[6];
    const float* b2   = (const float*)d_in[7];
    const float* W3   = (const float*)d_in[8];
    const float* b3   = (const float*)d_in[9];
    const float* fcw1 = (const float*)d_in[10];
    const float* fcb1 = (const float*)d_in[11];
    const float* fcw2 = (const float*)d_in[12];
    const float* fcb2 = (const float*)d_in[13];

    const int* src = ei;
    const int* dst = ei + N_EDGES;

    float* p = (float*)d_ws;
    float* w   = p; p += N_EDGES;
    float* deg = p; p += N_NODES;
    const size_t NB = (size_t)N_NODES * 64;
    float* T1  = p; p += NB;
    float* T2  = p; p += NB;
    float* T3  = p; p += NB;
    float* OUT = p; p += NB;
    float* HA  = p; p += NB;
    float* HB  = p; p += NB;
    float* pooled = p; p += (size_t)N_GRAPHS * 64;
    float* cnt    = p; p += N_GRAPHS;

    const int TPB = 256;

    hipMemsetAsync(deg, 0, N_NODES * sizeof(float), stream);
    hipLaunchKernelGGL(deg_kernel, dim3(cdiv_ll(N_EDGES, TPB)), dim3(TPB), 0, stream, src, dst, deg);
    hipLaunchKernelGGL(dinv_kernel, dim3(cdiv_ll(N_NODES, TPB)), dim3(TPB), 0, stream, deg);
    hipLaunchKernelGGL(edgew_kernel, dim3(cdiv_ll(N_EDGES, TPB)), dim3(TPB), 0, stream, src, dst, deg, w);

    run_cheb<4, 32>(src, dst, w, x,  T1, T2, T3, OUT, W1, b1, HA, stream);
    run_cheb<32, 64>(src, dst, w, HA, T1, T2, T3, OUT, W2, b2, HB, stream);
    run_cheb<64, 64>(src, dst, w, HB, T1, T2, T3, OUT, W3, b3, HA, stream);

    hipMemsetAsync(pooled, 0, (size_t)(N_GRAPHS * 64 + N_GRAPHS) * sizeof(float), stream);
    hipLaunchKernelGGL(pool_kernel, dim3(cdiv_ll((long long)N_NODES * 64, TPB)), dim3(TPB), 0,
                       stream, HA, batch, pooled, cnt);
    hipLaunchKernelGGL(fc_kernel, dim3(N_GRAPHS), dim3(32), 0, stream,
                       pooled, cnt, fcw1, fcb1, fcw2, fcb2, (float*)d_out);
}

// Round 2
// 1165.095 us; speedup vs baseline: 2.9253x; 2.9253x over previous
//
#include <hip/hip_runtime.h>

// ChebNet on MI355X — Round 2: CSR-gather instead of atomic scatter.
// Build dst-CSR on device, then L(z) = per-node gather (wave per node, lane=feat).
// Fused recurrence epilogue + fused 5-way einsum/bias/relu combine per layer.

constexpr int N_NODES  = 50000;
constexpr int N_EDGES  = 1600000;
constexpr int N_GRAPHS = 128;

static inline int cdiv(long long a, int b) { return (int)((a + b - 1) / b); }

// ---- CSR build ---------------------------------------------------------

__global__ void hist_kernel(const int* __restrict__ src, const int* __restrict__ dst,
                            int* __restrict__ deg_i, int* __restrict__ cnt_i) {
    int e = blockIdx.x * blockDim.x + threadIdx.x;
    if (e < N_EDGES) {
        int s = src[e], d = dst[e];
        if (s != d) {
            atomicAdd(&deg_i[s], 1);   // out-degree (for sym norm)
            atomicAdd(&cnt_i[d], 1);   // in-degree (CSR row sizes)
        }
    }
}

__global__ void dinv_kernel(const int* __restrict__ deg_i, float* __restrict__ dinv) {
    int i = blockIdx.x * blockDim.x + threadIdx.x;
    if (i < N_NODES) {
        int d = deg_i[i];
        dinv[i] = d > 0 ? rsqrtf((float)d) : 0.f;
    }
}

// Single-block inclusive scan over cnt -> row offsets (row[0]=0, row[i+1]=sum<=i)
__global__ void scan_kernel(const int* __restrict__ cnt, int* __restrict__ row) {
    __shared__ int buf[1024];
    __shared__ int carry;
    int t = threadIdx.x;
    if (t == 0) { carry = 0; row[0] = 0; }
    __syncthreads();
    for (int base = 0; base < N_NODES; base += 1024) {
        int i = base + t;
        int v = (i < N_NODES) ? cnt[i] : 0;
        buf[t] = v;
        __syncthreads();
        for (int off = 1; off < 1024; off <<= 1) {
            int add = (t >= off) ? buf[t - off] : 0;
            __syncthreads();
            buf[t] += add;
            __syncthreads();
        }
        if (i < N_NODES) row[i + 1] = carry + buf[t];
        __syncthreads();
        if (t == 1023) carry += buf[1023];
        __syncthreads();
    }
}

// Place each non-self edge into CSR slot of its dst; entry = {w_e, src}
__global__ void place_kernel(const int* __restrict__ src, const int* __restrict__ dst,
                             const float* __restrict__ dinv, const int* __restrict__ row,
                             int* __restrict__ cursor, float2* __restrict__ csr) {
    int e = blockIdx.x * blockDim.x + threadIdx.x;
    if (e < N_EDGES) {
        int s = src[e], d = dst[e];
        if (s != d) {
            float w = -dinv[s] * dinv[d];
            int pos = row[d] + atomicAdd(&cursor[d], 1);
            csr[pos] = make_float2(w, __int_as_float(s));
        }
    }
}

// ---- L(z) gathers ------------------------------------------------------

// out[n,f] = alpha * sum_e w_e z[src_e,f]  (+ beta * prev[n,f])
// F in {32, 64}: F lanes per node.
template <int F>
__global__ void gather_kernel(const int* __restrict__ row, const float2* __restrict__ csr,
                              const float* __restrict__ z, const float* __restrict__ prev,
                              float* __restrict__ out, float alpha, float beta) {
    constexpr int NPB = 256 / F;
    int node = blockIdx.x * NPB + threadIdx.x / F;
    int lane = threadIdx.x % F;
    if (node >= N_NODES) return;
    int e0 = row[node], e1 = row[node + 1];
    float acc = 0.f;
#pragma unroll 4
    for (int e = e0; e < e1; ++e) {
        float2 ew = csr[e];
        acc = fmaf(ew.x, z[(size_t)__float_as_int(ew.y) * F + lane], acc);
    }
    float r = alpha * acc;
    if (beta != 0.f) r = fmaf(beta, prev[(size_t)node * F + lane], r);
    out[(size_t)node * F + lane] = r;
}

// F=4 specialization: one thread per node, float4 rows.
__global__ void gather4_kernel(const int* __restrict__ row, const float2* __restrict__ csr,
                               const float* __restrict__ z, const float* __restrict__ prev,
                               float* __restrict__ out, float alpha, float beta) {
    int node = blockIdx.x * blockDim.x + threadIdx.x;
    if (node >= N_NODES) return;
    int e0 = row[node], e1 = row[node + 1];
    const float4* z4 = (const float4*)z;
    float4 a = make_float4(0.f, 0.f, 0.f, 0.f);
#pragma unroll 4
    for (int e = e0; e < e1; ++e) {
        float2 ew = csr[e];
        float4 zz = z4[__float_as_int(ew.y)];
        a.x = fmaf(ew.x, zz.x, a.x);
        a.y = fmaf(ew.x, zz.y, a.y);
        a.z = fmaf(ew.x, zz.z, a.z);
        a.w = fmaf(ew.x, zz.w, a.w);
    }
    float4 r = make_float4(alpha * a.x, alpha * a.y, alpha * a.z, alpha * a.w);
    if (beta != 0.f) {
        const float4 p = ((const float4*)prev)[node];
        r.x = fmaf(beta, p.x, r.x);
        r.y = fmaf(beta, p.y, r.y);
        r.z = fmaf(beta, p.z, r.z);
        r.w = fmaf(beta, p.w, r.w);
    }
    ((float4*)out)[node] = r;
}

// ---- fused 5-way einsum + bias + relu ---------------------------------

// out[n,o] = relu(b[o] + sum_k sum_f T_k[n,f] * W[k,f,o]) ; 1024-thr blocks,
// one W_k chunk staged in LDS at a time. Safe for out aliasing any T_k
// (each wave reads only its own node's rows before writing them).
template <int FI, int FO>
__global__ void combine_kernel(const float* __restrict__ X, const float* __restrict__ T1,
                               const float* __restrict__ T2, const float* __restrict__ T3,
                               const float* __restrict__ T4, const float* __restrict__ W,
                               const float* __restrict__ b, float* __restrict__ out) {
    __shared__ float Ws[FI * FO];
    constexpr int NPB = 1024 / FO;
    int node = blockIdx.x * NPB + threadIdx.x / FO;
    int o = threadIdx.x % FO;
    const float* Ts[5] = {X, T1, T2, T3, T4};
    float acc = b[o];
#pragma unroll
    for (int k = 0; k < 5; ++k) {
        __syncthreads();
        for (int i = threadIdx.x; i < FI * FO; i += 1024) Ws[i] = W[k * FI * FO + i];
        __syncthreads();
        if (node < N_NODES) {
            const float* T = Ts[k] + (size_t)node * FI;
#pragma unroll
            for (int f = 0; f < FI; ++f) acc = fmaf(T[f], Ws[f * FO + o], acc);
        }
    }
    if (node < N_NODES) out[(size_t)node * FO + o] = fmaxf(acc, 0.f);
}

// ---- pooling + MLP -----------------------------------------------------

// batch is sorted: per-wave segmented reduction over a contiguous node strip.
__global__ void pool_kernel(const float* __restrict__ h, const int* __restrict__ batch,
                            float* __restrict__ pooled, float* __restrict__ cntf) {
    int wid = blockIdx.x * (blockDim.x / 64) + (threadIdx.x >> 6);
    int lane = threadIdx.x & 63;
    int nwaves = gridDim.x * (blockDim.x / 64);
    int per = (N_NODES + nwaves - 1) / nwaves;
    int n0 = wid * per;
    int n1 = min(n0 + per, N_NODES);
    if (n0 >= n1) return;
    int cur = batch[n0];
    float acc = 0.f;
    int c = 0;
    for (int n = n0; n < n1; ++n) {
        int g = batch[n];
        if (g != cur) {
            atomicAdd(&pooled[cur * 64 + lane], acc);
            if (lane == 0) atomicAdd(&cntf[cur], (float)c);
            acc = 0.f; c = 0; cur = g;
        }
        acc += h[(size_t)n * 64 + lane];
        ++c;
    }
    atomicAdd(&pooled[cur * 64 + lane], acc);
    if (lane == 0) atomicAdd(&cntf[cur], (float)c);
}

__global__ void fc_kernel(const float* __restrict__ pooled, const float* __restrict__ cnt,
                          const float* __restrict__ w1, const float* __restrict__ b1,
                          const float* __restrict__ w2, const float* __restrict__ b2,
                          float* __restrict__ out) {
    int g = blockIdx.x;
    int t = threadIdx.x;  // 32
    __shared__ float hid[32];
    float c = fmaxf(cnt[g], 1.0f);
    float acc = b1[t];
    for (int f = 0; f < 64; ++f) acc = fmaf(pooled[g * 64 + f] / c, w1[f * 32 + t], acc);
    hid[t] = fmaxf(acc, 0.f);
    __syncthreads();
    if (t == 0) {
        float acc2 = b2[0];
        for (int o = 0; o < 32; ++o) acc2 = fmaf(hid[o], w2[o], acc2);
        out[g] = acc2;
    }
}

// ---- host orchestration ------------------------------------------------

template <int FI, int FO>
static void run_layer(const int* row, const float2* csr, const float* X,
                      float* T1, float* T2, float* T3, float* T4,
                      const float* W, const float* b, float* out, hipStream_t stream) {
    if constexpr (FI == 4) {
        dim3 g(cdiv(N_NODES, 256)), blk(256);
        hipLaunchKernelGGL(gather4_kernel, g, blk, 0, stream, row, csr, X,  X,  T1, 1.f, 0.f);
        hipLaunchKernelGGL(gather4_kernel, g, blk, 0, stream, row, csr, T1, X,  T2, 2.f, -1.f);
        hipLaunchKernelGGL(gather4_kernel, g, blk, 0, stream, row, csr, T2, T1, T3, 2.f, -1.f);
        hipLaunchKernelGGL(gather4_kernel, g, blk, 0, stream, row, csr, T3, T2, T4, 2.f, -1.f);
    } else {
        constexpr int NPB = 256 / FI;
        dim3 g(cdiv(N_NODES, NPB)), blk(256);
        hipLaunchKernelGGL((gather_kernel<FI>), g, blk, 0, stream, row, csr, X,  X,  T1, 1.f, 0.f);
        hipLaunchKernelGGL((gather_kernel<FI>), g, blk, 0, stream, row, csr, T1, X,  T2, 2.f, -1.f);
        hipLaunchKernelGGL((gather_kernel<FI>), g, blk, 0, stream, row, csr, T2, T1, T3, 2.f, -1.f);
        hipLaunchKernelGGL((gather_kernel<FI>), g, blk, 0, stream, row, csr, T3, T2, T4, 2.f, -1.f);
    }
    hipLaunchKernelGGL((combine_kernel<FI, FO>), dim3(cdiv(N_NODES, 1024 / FO)), dim3(1024), 0,
                       stream, X, T1, T2, T3, T4, W, b, out);
}

extern "C" void kernel_launch(void* const* d_in, const int* in_sizes, int n_in,
                              void* d_out, int out_size, void* d_ws, size_t ws_size,
                              hipStream_t stream) {
    const float* x    = (const float*)d_in[0];
    const int*   ei   = (const int*)d_in[1];
    const int*   batch= (const int*)d_in[2];
    const float* W1   = (const float*)d_in[4];
    const float* b1   = (const float*)d_in[5];
    const float* W2   = (const float*)d_in[6];
    const float* b2   = (const float*)d_in[7];
    const float* W3   = (const float*)d_in[8];
    const float* b3   = (const float*)d_in[9];
    const float* fcw1 = (const float*)d_in[10];
    const float* fcb1 = (const float*)d_in[11];
    const float* fcw2 = (const float*)d_in[12];
    const float* fcb2 = (const float*)d_in[13];

    const int* src = ei;
    const int* dst = ei + N_EDGES;

    // workspace layout (floats); csr/T offsets kept 16B aligned
    float* base = (float*)d_ws;
    int*    deg_i  = (int*)(base + 0);              // 50000
    float*  dinv   = base + 50000;                  // 50000
    int*    cnt_i  = (int*)(base + 100000);         // 50000 (hist, then cursor)
    int*    row    = (int*)(base + 150000);         // 50002 (padded)
    float2* csr    = (float2*)(base + 200002);      // 1.6M float2 = 3.2M floats
    float*  T1     = base + 3400004;                // 3.2M each
    float*  T2     = base + 6600004;
    float*  T3     = base + 9800004;
    float*  T4     = base + 13000004;
    float*  H1     = T4 + 1600000;                  // 1.6M (layer1 out, F=32) — upper half of T4 slot
    float*  H2     = base + 16200004;               // 3.2M (layer2 out, F=64)
    float*  pooled = base + 19400004;               // 8192
    float*  cntf   = base + 19408196;               // 128

    const int TPB = 256;

    hipMemsetAsync(deg_i, 0, 2 * 50000 * sizeof(int), stream);  // deg_i + dinv area ok
    hipMemsetAsync(cnt_i, 0, 50000 * sizeof(int), stream);
    hipLaunchKernelGGL(hist_kernel, dim3(cdiv(N_EDGES, TPB)), dim3(TPB), 0, stream, src, dst, deg_i, cnt_i);
    hipLaunchKernelGGL(dinv_kernel, dim3(cdiv(N_NODES, TPB)), dim3(TPB), 0, stream, deg_i, dinv);
    hipLaunchKernelGGL(scan_kernel, dim3(1), dim3(1024), 0, stream, cnt_i, row);
    hipMemsetAsync(cnt_i, 0, 50000 * sizeof(int), stream);  // reuse as cursor
    hipLaunchKernelGGL(place_kernel, dim3(cdiv(N_EDGES, TPB)), dim3(TPB), 0, stream,
                       src, dst, dinv, row, cnt_i, csr);

    run_layer<4, 32>(row, csr, x,  T1, T2, T3, T4, W1, b1, H1, stream);
    run_layer<32, 64>(row, csr, H1, T1, T2, T3, T4, W2, b2, H2, stream);
    run_layer<64, 64>(row, csr, H2, T1, T2, T3, T4, W3, b3, T1, stream);  // out in-place into T1

    hipMemsetAsync(pooled, 0, (8192 + 128) * sizeof(float), stream);
    hipLaunchKernelGGL(pool_kernel, dim3(128), dim3(256), 0, stream, T1, batch, pooled, cntf);
    hipLaunchKernelGGL(fc_kernel, dim3(N_GRAPHS), dim3(32), 0, stream,
                       pooled, cntf, fcw1, fcb1, fcw2, fcb2, (float*)d_out);
}

// Round 3
// 956.705 us; speedup vs baseline: 3.5625x; 1.2178x over previous
//
#include <hip/hip_runtime.h>

// ChebNet on MI355X — Round 3: LDS-tiled register-blocked combine GEMM,
// multi-block scan. Gathers/CSR unchanged from R2.

constexpr int N_NODES  = 50000;
constexpr int N_EDGES  = 1600000;
constexpr int N_GRAPHS = 128;

static inline int cdiv(long long a, int b) { return (int)((a + b - 1) / b); }

// ---- CSR build ---------------------------------------------------------

__global__ void hist_kernel(const int* __restrict__ src, const int* __restrict__ dst,
                            int* __restrict__ deg_i, int* __restrict__ cnt_i) {
    int e = blockIdx.x * blockDim.x + threadIdx.x;
    if (e < N_EDGES) {
        int s = src[e], d = dst[e];
        if (s != d) {
            atomicAdd(&deg_i[s], 1);
            atomicAdd(&cnt_i[d], 1);
        }
    }
}

__global__ void dinv_kernel(const int* __restrict__ deg_i, float* __restrict__ dinv) {
    int i = blockIdx.x * blockDim.x + threadIdx.x;
    if (i < N_NODES) {
        int d = deg_i[i];
        dinv[i] = d > 0 ? rsqrtf((float)d) : 0.f;
    }
}

// ---- 3-phase scan: row[i+1] = inclusive_sum(cnt[0..i]), row[0]=0 -------

constexpr int SCAN_B = 256;
constexpr int SCAN_NB = (N_NODES + SCAN_B - 1) / SCAN_B;  // 196

__global__ void scan_block_kernel(const int* __restrict__ cnt, int* __restrict__ row,
                                  int* __restrict__ bsum) {
    __shared__ int buf[SCAN_B];
    int t = threadIdx.x;
    int i = blockIdx.x * SCAN_B + t;
    buf[t] = (i < N_NODES) ? cnt[i] : 0;
    __syncthreads();
    for (int off = 1; off < SCAN_B; off <<= 1) {
        int a = (t >= off) ? buf[t - off] : 0;
        __syncthreads();
        buf[t] += a;
        __syncthreads();
    }
    if (i < N_NODES) row[i + 1] = buf[t];
    if (t == SCAN_B - 1) bsum[blockIdx.x] = buf[t];
    if (i == 0) row[0] = 0;
}

__global__ void scan_sums_kernel(int* __restrict__ bsum) {
    __shared__ int buf[SCAN_NB];
    int t = threadIdx.x;  // 256 >= SCAN_NB
    int v = (t < SCAN_NB) ? bsum[t] : 0;
    if (t < SCAN_NB) buf[t] = v;
    __syncthreads();
    for (int off = 1; off < SCAN_NB; off <<= 1) {
        int a = (t >= off && t < SCAN_NB) ? buf[t - off] : 0;
        __syncthreads();
        if (t < SCAN_NB) buf[t] += a;
        __syncthreads();
    }
    if (t < SCAN_NB) bsum[t] = buf[t];
}

__global__ void scan_add_kernel(int* __restrict__ row, const int* __restrict__ bsum) {
    int i = blockIdx.x * SCAN_B + threadIdx.x;
    if (blockIdx.x > 0 && i < N_NODES) row[i + 1] += bsum[blockIdx.x - 1];
}

__global__ void place_kernel(const int* __restrict__ src, const int* __restrict__ dst,
                             const float* __restrict__ dinv, const int* __restrict__ row,
                             int* __restrict__ cursor, float2* __restrict__ csr) {
    int e = blockIdx.x * blockDim.x + threadIdx.x;
    if (e < N_EDGES) {
        int s = src[e], d = dst[e];
        if (s != d) {
            float w = -dinv[s] * dinv[d];
            int pos = row[d] + atomicAdd(&cursor[d], 1);
            csr[pos] = make_float2(w, __int_as_float(s));
        }
    }
}

// ---- L(z) gathers ------------------------------------------------------

template <int F>
__global__ void gather_kernel(const int* __restrict__ row, const float2* __restrict__ csr,
                              const float* __restrict__ z, const float* __restrict__ prev,
                              float* __restrict__ out, float alpha, float beta) {
    constexpr int NPB = 256 / F;
    int node = blockIdx.x * NPB + threadIdx.x / F;
    int lane = threadIdx.x % F;
    if (node >= N_NODES) return;
    int e0 = row[node], e1 = row[node + 1];
    float acc = 0.f;
#pragma unroll 4
    for (int e = e0; e < e1; ++e) {
        float2 ew = csr[e];
        acc = fmaf(ew.x, z[(size_t)__float_as_int(ew.y) * F + lane], acc);
    }
    float r = alpha * acc;
    if (beta != 0.f) r = fmaf(beta, prev[(size_t)node * F + lane], r);
    out[(size_t)node * F + lane] = r;
}

__global__ void gather4_kernel(const int* __restrict__ row, const float2* __restrict__ csr,
                               const float* __restrict__ z, const float* __restrict__ prev,
                               float* __restrict__ out, float alpha, float beta) {
    int node = blockIdx.x * blockDim.x + threadIdx.x;
    if (node >= N_NODES) return;
    int e0 = row[node], e1 = row[node + 1];
    const float4* z4 = (const float4*)z;
    float4 a = make_float4(0.f, 0.f, 0.f, 0.f);
#pragma unroll 4
    for (int e = e0; e < e1; ++e) {
        float2 ew = csr[e];
        float4 zz = z4[__float_as_int(ew.y)];
        a.x = fmaf(ew.x, zz.x, a.x);
        a.y = fmaf(ew.x, zz.y, a.y);
        a.z = fmaf(ew.x, zz.z, a.z);
        a.w = fmaf(ew.x, zz.w, a.w);
    }
    float4 r = make_float4(alpha * a.x, alpha * a.y, alpha * a.z, alpha * a.w);
    if (beta != 0.f) {
        const float4 p = ((const float4*)prev)[node];
        r.x = fmaf(beta, p.x, r.x);
        r.y = fmaf(beta, p.y, r.y);
        r.z = fmaf(beta, p.z, r.z);
        r.w = fmaf(beta, p.w, r.w);
    }
    ((float4*)out)[node] = r;
}

// ---- combine: out[n,o] = relu(b[o] + sum_k T_k[n,:] @ W[k,:,o]) --------
// FO=64 tiled GEMM: 256 threads, 64-node x 64-out tile, 4x4 register tile.
// Thread (tn = t&15, to = t>>4): nodes {tn+16i}, outputs {4*to+j}.
// LDS: T tile padded to stride FI+4 (16B-aligned rows, 2-way banks = free),
// W_k slice [FI][64]. Safe when out aliases an input T (block-private rows).

template <int FI>
__global__ __launch_bounds__(256) void combine64_kernel(
        const float* __restrict__ X, const float* __restrict__ T1,
        const float* __restrict__ T2, const float* __restrict__ T3,
        const float* __restrict__ T4, const float* __restrict__ W,
        const float* __restrict__ b, float* __restrict__ out) {
    constexpr int FO = 64;
    constexpr int TS = FI + 4;
    __shared__ float Ts[64 * TS];
    __shared__ float Ws[FI * FO];
    const int t = threadIdx.x;
    const int tn = t & 15;
    const int to = t >> 4;
    const int n_base = blockIdx.x * 64;
    const float* Tk[5] = {X, T1, T2, T3, T4};

    float acc[4][4];
    {
        const float4 bb = *(const float4*)(b + 4 * to);
#pragma unroll
        for (int i = 0; i < 4; ++i) {
            acc[i][0] = bb.x; acc[i][1] = bb.y; acc[i][2] = bb.z; acc[i][3] = bb.w;
        }
    }

#pragma unroll
    for (int k = 0; k < 5; ++k) {
        __syncthreads();
        // stage T_k tile (64 x FI contiguous region), guarded for last block
        {
            const float4* s4 = (const float4*)(Tk[k] + (size_t)n_base * FI);
            constexpr int NV = 64 * FI / 4;
#pragma unroll
            for (int idx = t; idx < NV; idx += 256) {
                int r = idx / (FI / 4), c = idx % (FI / 4);
                float4 v = make_float4(0.f, 0.f, 0.f, 0.f);
                if (n_base + r < N_NODES) v = s4[idx];
                *(float4*)(Ts + r * TS + 4 * c) = v;
            }
            const float4* w4 = (const float4*)(W + (size_t)k * FI * FO);
            constexpr int WV = FI * FO / 4;
#pragma unroll
            for (int idx = t; idx < WV; idx += 256) *(float4*)(Ws + 4 * idx) = w4[idx];
        }
        __syncthreads();
#pragma unroll
        for (int f0 = 0; f0 < FI; f0 += 4) {
            float tv[4][4];
#pragma unroll
            for (int i = 0; i < 4; ++i) {
                float4 q = *(const float4*)(Ts + (tn + 16 * i) * TS + f0);
                tv[i][0] = q.x; tv[i][1] = q.y; tv[i][2] = q.z; tv[i][3] = q.w;
            }
#pragma unroll
            for (int j = 0; j < 4; ++j) {
                float4 w = *(const float4*)(Ws + (f0 + j) * FO + 4 * to);
#pragma unroll
                for (int i = 0; i < 4; ++i) {
                    acc[i][0] = fmaf(tv[i][j], w.x, acc[i][0]);
                    acc[i][1] = fmaf(tv[i][j], w.y, acc[i][1]);
                    acc[i][2] = fmaf(tv[i][j], w.z, acc[i][2]);
                    acc[i][3] = fmaf(tv[i][j], w.w, acc[i][3]);
                }
            }
        }
    }
    __syncthreads();
#pragma unroll
    for (int i = 0; i < 4; ++i) {
        int n = n_base + tn + 16 * i;
        if (n < N_NODES) {
            float4 r = make_float4(fmaxf(acc[i][0], 0.f), fmaxf(acc[i][1], 0.f),
                                   fmaxf(acc[i][2], 0.f), fmaxf(acc[i][3], 0.f));
            *(float4*)(out + (size_t)n * FO + 4 * to) = r;
        }
    }
}

// layer-1 combine: FI=4, FO=32. Thread = (node, o); T rows via float4.
__global__ void combine432_kernel(const float* __restrict__ X, const float* __restrict__ T1,
                                  const float* __restrict__ T2, const float* __restrict__ T3,
                                  const float* __restrict__ T4, const float* __restrict__ W,
                                  const float* __restrict__ b, float* __restrict__ out) {
    __shared__ float Ws[5 * 4 * 32];
    int t = threadIdx.x;  // 256 = 8 nodes x 32 outs
    for (int i = t; i < 5 * 4 * 32; i += 256) Ws[i] = W[i];
    __syncthreads();
    int node = blockIdx.x * 8 + (t >> 5);
    int o = t & 31;
    if (node >= N_NODES) return;
    const float4* Tk[5] = {(const float4*)X, (const float4*)T1, (const float4*)T2,
                           (const float4*)T3, (const float4*)T4};
    float acc = b[o];
#pragma unroll
    for (int k = 0; k < 5; ++k) {
        float4 q = Tk[k][node];
        const float* w = Ws + k * 128 + o;
        acc = fmaf(q.x, w[0], acc);
        acc = fmaf(q.y, w[32], acc);
        acc = fmaf(q.z, w[64], acc);
        acc = fmaf(q.w, w[96], acc);
    }
    out[(size_t)node * 32 + o] = fmaxf(acc, 0.f);
}

// ---- pooling + MLP -----------------------------------------------------

__global__ void pool_kernel(const float* __restrict__ h, const int* __restrict__ batch,
                            float* __restrict__ pooled, float* __restrict__ cntf) {
    int wid = blockIdx.x * (blockDim.x / 64) + (threadIdx.x >> 6);
    int lane = threadIdx.x & 63;
    int nwaves = gridDim.x * (blockDim.x / 64);
    int per = (N_NODES + nwaves - 1) / nwaves;
    int n0 = wid * per;
    int n1 = min(n0 + per, N_NODES);
    if (n0 >= n1) return;
    int cur = batch[n0];
    float acc = 0.f;
    int c = 0;
    for (int n = n0; n < n1; ++n) {
        int g = batch[n];
        if (g != cur) {
            atomicAdd(&pooled[cur * 64 + lane], acc);
            if (lane == 0) atomicAdd(&cntf[cur], (float)c);
            acc = 0.f; c = 0; cur = g;
        }
        acc += h[(size_t)n * 64 + lane];
        ++c;
    }
    atomicAdd(&pooled[cur * 64 + lane], acc);
    if (lane == 0) atomicAdd(&cntf[cur], (float)c);
}

__global__ void fc_kernel(const float* __restrict__ pooled, const float* __restrict__ cnt,
                          const float* __restrict__ w1, const float* __restrict__ b1,
                          const float* __restrict__ w2, const float* __restrict__ b2,
                          float* __restrict__ out) {
    int g = blockIdx.x;
    int t = threadIdx.x;  // 32
    __shared__ float hid[32];
    float c = fmaxf(cnt[g], 1.0f);
    float acc = b1[t];
    for (int f = 0; f < 64; ++f) acc = fmaf(pooled[g * 64 + f] / c, w1[f * 32 + t], acc);
    hid[t] = fmaxf(acc, 0.f);
    __syncthreads();
    if (t == 0) {
        float acc2 = b2[0];
        for (int o = 0; o < 32; ++o) acc2 = fmaf(hid[o], w2[o], acc2);
        out[g] = acc2;
    }
}

// ---- host orchestration ------------------------------------------------

template <int FI, int FO>
static void run_layer(const int* row, const float2* csr, const float* X,
                      float* T1, float* T2, float* T3, float* T4,
                      const float* W, const float* b, float* out, hipStream_t stream) {
    if constexpr (FI == 4) {
        dim3 g(cdiv(N_NODES, 256)), blk(256);
        hipLaunchKernelGGL(gather4_kernel, g, blk, 0, stream, row, csr, X,  X,  T1, 1.f, 0.f);
        hipLaunchKernelGGL(gather4_kernel, g, blk, 0, stream, row, csr, T1, X,  T2, 2.f, -1.f);
        hipLaunchKernelGGL(gather4_kernel, g, blk, 0, stream, row, csr, T2, T1, T3, 2.f, -1.f);
        hipLaunchKernelGGL(gather4_kernel, g, blk, 0, stream, row, csr, T3, T2, T4, 2.f, -1.f);
    } else {
        constexpr int NPB = 256 / FI;
        dim3 g(cdiv(N_NODES, NPB)), blk(256);
        hipLaunchKernelGGL((gather_kernel<FI>), g, blk, 0, stream, row, csr, X,  X,  T1, 1.f, 0.f);
        hipLaunchKernelGGL((gather_kernel<FI>), g, blk, 0, stream, row, csr, T1, X,  T2, 2.f, -1.f);
        hipLaunchKernelGGL((gather_kernel<FI>), g, blk, 0, stream, row, csr, T2, T1, T3, 2.f, -1.f);
        hipLaunchKernelGGL((gather_kernel<FI>), g, blk, 0, stream, row, csr, T3, T2, T4, 2.f, -1.f);
    }
    if constexpr (FO == 64) {
        hipLaunchKernelGGL((combine64_kernel<FI>), dim3(cdiv(N_NODES, 64)), dim3(256), 0,
                           stream, X, T1, T2, T3, T4, W, b, out);
    } else {
        hipLaunchKernelGGL(combine432_kernel, dim3(cdiv(N_NODES, 8)), dim3(256), 0,
                           stream, X, T1, T2, T3, T4, W, b, out);
    }
}

extern "C" void kernel_launch(void* const* d_in, const int* in_sizes, int n_in,
                              void* d_out, int out_size, void* d_ws, size_t ws_size,
                              hipStream_t stream) {
    const float* x    = (const float*)d_in[0];
    const int*   ei   = (const int*)d_in[1];
    const int*   batch= (const int*)d_in[2];
    const float* W1   = (const float*)d_in[4];
    const float* b1   = (const float*)d_in[5];
    const float* W2   = (const float*)d_in[6];
    const float* b2   = (const float*)d_in[7];
    const float* W3   = (const float*)d_in[8];
    const float* b3   = (const float*)d_in[9];
    const float* fcw1 = (const float*)d_in[10];
    const float* fcb1 = (const float*)d_in[11];
    const float* fcw2 = (const float*)d_in[12];
    const float* fcb2 = (const float*)d_in[13];

    const int* src = ei;
    const int* dst = ei + N_EDGES;

    float* base = (float*)d_ws;
    int*    deg_i  = (int*)(base + 0);              // 50000
    float*  dinv   = base + 50000;                  // 50000
    int*    cnt_i  = (int*)(base + 100000);         // 50000 (hist, then cursor)
    int*    row    = (int*)(base + 150000);         // 50002 (padded to 50004)
    int*    bsum   = (int*)(base + 200004);         // 196 (pad to 252)
    float2* csr    = (float2*)(base + 200256);      // 1.6M float2
    float*  T1     = base + 3400256;
    float*  T2     = base + 6600256;
    float*  T3     = base + 9800256;
    float*  T4     = base + 13000256;
    float*  H1     = T4 + 1600000;                  // layer1 out (F=32) in T4's top half
    float*  H2     = base + 16200256;
    float*  pooled = base + 19400256;
    float*  cntf   = base + 19408448;

    const int TPB = 256;

    hipMemsetAsync(deg_i, 0, 50000 * sizeof(int), stream);
    hipMemsetAsync(cnt_i, 0, 50000 * sizeof(int), stream);
    hipLaunchKernelGGL(hist_kernel, dim3(cdiv(N_EDGES, TPB)), dim3(TPB), 0, stream, src, dst, deg_i, cnt_i);
    hipLaunchKernelGGL(dinv_kernel, dim3(cdiv(N_NODES, TPB)), dim3(TPB), 0, stream, deg_i, dinv);
    hipLaunchKernelGGL(scan_block_kernel, dim3(SCAN_NB), dim3(SCAN_B), 0, stream, cnt_i, row, bsum);
    hipLaunchKernelGGL(scan_sums_kernel, dim3(1), dim3(256), 0, stream, bsum);
    hipLaunchKernelGGL(scan_add_kernel, dim3(SCAN_NB), dim3(SCAN_B), 0, stream, row, bsum);
    hipMemsetAsync(cnt_i, 0, 50000 * sizeof(int), stream);  // reuse as cursor
    hipLaunchKernelGGL(place_kernel, dim3(cdiv(N_EDGES, TPB)), dim3(TPB), 0, stream,
                       src, dst, dinv, row, cnt_i, csr);

    run_layer<4, 32>(row, csr, x,  T1, T2, T3, T4, W1, b1, H1, stream);
    run_layer<32, 64>(row, csr, H1, T1, T2, T3, T4, W2, b2, H2, stream);
    run_layer<64, 64>(row, csr, H2, T1, T2, T3, T4, W3, b3, T1, stream);

    hipMemsetAsync(pooled, 0, (8192 + 128) * sizeof(float), stream);
    hipLaunchKernelGGL(pool_kernel, dim3(128), dim3(256), 0, stream, T1, batch, pooled, cntf);
    hipLaunchKernelGGL(fc_kernel, dim3(N_GRAPHS), dim3(32), 0, stream,
                       pooled, cntf, fcw1, fcb1, fcw2, fcb2, (float*)d_out);
}

// Round 4
// 904.370 us; speedup vs baseline: 3.7686x; 1.0579x over previous
//
#include <hip/hip_runtime.h>

// ChebNet on MI355X — Round 4: atomic-free CSR build via LDS-binned counting
// sort (byte-packed histograms + per-block prefix tables). Gathers/combine
// unchanged from R3.

constexpr int N_NODES  = 50000;
constexpr int N_EDGES  = 1600000;
constexpr int N_GRAPHS = 128;

constexpr int NB_H = 256;                 // histogram/place blocks
constexpr int EPB  = N_EDGES / NB_H;      // 6250 edges per block (exact)
constexpr int NW   = (N_NODES + 3) / 4;   // 12500 packed words (4 u8 bins each)

static inline int cdiv(long long a, int b) { return (int)((a + b - 1) / b); }

// ---- CSR build (atomic-free at device scope) ---------------------------

template <int USE_DST>
__global__ __launch_bounds__(256) void hist_kernel(const int* __restrict__ src,
                                                   const int* __restrict__ dst,
                                                   unsigned* __restrict__ H) {
    __shared__ unsigned lds[NW];  // 50 KB: 4 byte-bins per word
    const int b = blockIdx.x, t = threadIdx.x;
    for (int i = t; i < NW; i += 256) lds[i] = 0;
    __syncthreads();
    const int e0 = b * EPB, e1 = e0 + EPB;
    for (int e = e0 + t; e < e1; e += 256) {
        int s = src[e], d = dst[e];
        if (s != d) {
            int key = USE_DST ? d : s;
            atomicAdd(&lds[key >> 2], 1u << (8 * (key & 3)));
        }
    }
    __syncthreads();
    unsigned* Hb = H + (size_t)b * NW;
    for (int i = t; i < NW; i += 256) Hb[i] = lds[i];
}

// sum byte-fields over blocks -> out-degree -> dinv (fused)
__global__ void merge_src_kernel(const unsigned* __restrict__ H, float* __restrict__ dinv) {
    int i = blockIdx.x * blockDim.x + threadIdx.x;
    if (i >= NW) return;
    unsigned s0 = 0, s1 = 0, s2 = 0, s3 = 0;
    for (int b = 0; b < NB_H; ++b) {
        unsigned v = H[(size_t)b * NW + i];
        s0 += v & 0xff; s1 += (v >> 8) & 0xff; s2 += (v >> 16) & 0xff; s3 += v >> 24;
    }
    dinv[4 * i + 0] = s0 ? rsqrtf((float)s0) : 0.f;
    dinv[4 * i + 1] = s1 ? rsqrtf((float)s1) : 0.f;
    dinv[4 * i + 2] = s2 ? rsqrtf((float)s2) : 0.f;
    dinv[4 * i + 3] = s3 ? rsqrtf((float)s3) : 0.f;
}

// sum + exclusive prefix over blocks (byte-packed P), totals -> cnt
__global__ void merge_dst_kernel(const unsigned* __restrict__ H, unsigned* __restrict__ P,
                                 int* __restrict__ cnt) {
    int i = blockIdx.x * blockDim.x + threadIdx.x;
    if (i >= NW) return;
    unsigned p0 = 0, p1 = 0, p2 = 0, p3 = 0;
    for (int b = 0; b < NB_H; ++b) {
        size_t idx = (size_t)b * NW + i;
        unsigned v = H[idx];
        P[idx] = p0 | (p1 << 8) | (p2 << 16) | (p3 << 24);
        p0 += v & 0xff; p1 += (v >> 8) & 0xff; p2 += (v >> 16) & 0xff; p3 += v >> 24;
    }
    cnt[4 * i + 0] = (int)p0; cnt[4 * i + 1] = (int)p1;
    cnt[4 * i + 2] = (int)p2; cnt[4 * i + 3] = (int)p3;
}

// ---- 3-phase scan: row[i+1] = inclusive_sum(cnt[0..i]), row[0]=0 -------

constexpr int SCAN_B = 256;
constexpr int SCAN_NB = (N_NODES + SCAN_B - 1) / SCAN_B;  // 196

__global__ void scan_block_kernel(const int* __restrict__ cnt, int* __restrict__ row,
                                  int* __restrict__ bsum) {
    __shared__ int buf[SCAN_B];
    int t = threadIdx.x;
    int i = blockIdx.x * SCAN_B + t;
    buf[t] = (i < N_NODES) ? cnt[i] : 0;
    __syncthreads();
    for (int off = 1; off < SCAN_B; off <<= 1) {
        int a = (t >= off) ? buf[t - off] : 0;
        __syncthreads();
        buf[t] += a;
        __syncthreads();
    }
    if (i < N_NODES) row[i + 1] = buf[t];
    if (t == SCAN_B - 1) bsum[blockIdx.x] = buf[t];
    if (i == 0) row[0] = 0;
}

__global__ void scan_sums_kernel(int* __restrict__ bsum) {
    __shared__ int buf[SCAN_NB];
    int t = threadIdx.x;
    if (t < SCAN_NB) buf[t] = bsum[t];
    __syncthreads();
    for (int off = 1; off < SCAN_NB; off <<= 1) {
        int a = (t >= off && t < SCAN_NB) ? buf[t - off] : 0;
        __syncthreads();
        if (t < SCAN_NB) buf[t] += a;
        __syncthreads();
    }
    if (t < SCAN_NB) bsum[t] = buf[t];
}

__global__ void scan_add_kernel(int* __restrict__ row, const int* __restrict__ bsum) {
    int i = blockIdx.x * SCAN_B + threadIdx.x;
    if (blockIdx.x > 0 && i < N_NODES) row[i + 1] += bsum[blockIdx.x - 1];
}

// counting-sort placement: slot = row[d] + P[b][d] + lds_cursor[d]++
__global__ __launch_bounds__(256) void place_kernel(const int* __restrict__ src,
                                                    const int* __restrict__ dst,
                                                    const float* __restrict__ dinv,
                                                    const int* __restrict__ row,
                                                    const unsigned* __restrict__ P,
                                                    float2* __restrict__ csr) {
    __shared__ unsigned lds[NW];
    const int b = blockIdx.x, t = threadIdx.x;
    for (int i = t; i < NW; i += 256) lds[i] = 0;
    __syncthreads();
    const int e0 = b * EPB, e1 = e0 + EPB;
    const unsigned* Pb = P + (size_t)b * NW;
    for (int e = e0 + t; e < e1; e += 256) {
        int s = src[e], d = dst[e];
        if (s != d) {
            float w = -dinv[s] * dinv[d];
            int sh = 8 * (d & 3);
            unsigned old = atomicAdd(&lds[d >> 2], 1u << sh);
            unsigned cur = (old >> sh) & 0xff;
            unsigned pref = (Pb[d >> 2] >> sh) & 0xff;
            int pos = row[d] + (int)pref + (int)cur;
            csr[pos] = make_float2(w, __int_as_float(s));
        }
    }
}

// ---- L(z) gathers ------------------------------------------------------

template <int F>
__global__ void gather_kernel(const int* __restrict__ row, const float2* __restrict__ csr,
                              const float* __restrict__ z, const float* __restrict__ prev,
                              float* __restrict__ out, float alpha, float beta) {
    constexpr int NPB = 256 / F;
    int node = blockIdx.x * NPB + threadIdx.x / F;
    int lane = threadIdx.x % F;
    if (node >= N_NODES) return;
    int e0 = row[node], e1 = row[node + 1];
    float acc = 0.f;
#pragma unroll 4
    for (int e = e0; e < e1; ++e) {
        float2 ew = csr[e];
        acc = fmaf(ew.x, z[(size_t)__float_as_int(ew.y) * F + lane], acc);
    }
    float r = alpha * acc;
    if (beta != 0.f) r = fmaf(beta, prev[(size_t)node * F + lane], r);
    out[(size_t)node * F + lane] = r;
}

__global__ void gather4_kernel(const int* __restrict__ row, const float2* __restrict__ csr,
                               const float* __restrict__ z, const float* __restrict__ prev,
                               float* __restrict__ out, float alpha, float beta) {
    int node = blockIdx.x * blockDim.x + threadIdx.x;
    if (node >= N_NODES) return;
    int e0 = row[node], e1 = row[node + 1];
    const float4* z4 = (const float4*)z;
    float4 a = make_float4(0.f, 0.f, 0.f, 0.f);
#pragma unroll 4
    for (int e = e0; e < e1; ++e) {
        float2 ew = csr[e];
        float4 zz = z4[__float_as_int(ew.y)];
        a.x = fmaf(ew.x, zz.x, a.x);
        a.y = fmaf(ew.x, zz.y, a.y);
        a.z = fmaf(ew.x, zz.z, a.z);
        a.w = fmaf(ew.x, zz.w, a.w);
    }
    float4 r = make_float4(alpha * a.x, alpha * a.y, alpha * a.z, alpha * a.w);
    if (beta != 0.f) {
        const float4 p = ((const float4*)prev)[node];
        r.x = fmaf(beta, p.x, r.x);
        r.y = fmaf(beta, p.y, r.y);
        r.z = fmaf(beta, p.z, r.z);
        r.w = fmaf(beta, p.w, r.w);
    }
    ((float4*)out)[node] = r;
}

// ---- combine: out[n,o] = relu(b[o] + sum_k T_k[n,:] @ W[k,:,o]) --------

template <int FI>
__global__ __launch_bounds__(256) void combine64_kernel(
        const float* __restrict__ X, const float* __restrict__ T1,
        const float* __restrict__ T2, const float* __restrict__ T3,
        const float* __restrict__ T4, const float* __restrict__ W,
        const float* __restrict__ b, float* __restrict__ out) {
    constexpr int FO = 64;
    constexpr int TS = FI + 4;
    __shared__ float Ts[64 * TS];
    __shared__ float Ws[FI * FO];
    const int t = threadIdx.x;
    const int tn = t & 15;
    const int to = t >> 4;
    const int n_base = blockIdx.x * 64;
    const float* Tk[5] = {X, T1, T2, T3, T4};

    float acc[4][4];
    {
        const float4 bb = *(const float4*)(b + 4 * to);
#pragma unroll
        for (int i = 0; i < 4; ++i) {
            acc[i][0] = bb.x; acc[i][1] = bb.y; acc[i][2] = bb.z; acc[i][3] = bb.w;
        }
    }

#pragma unroll
    for (int k = 0; k < 5; ++k) {
        __syncthreads();
        {
            const float4* s4 = (const float4*)(Tk[k] + (size_t)n_base * FI);
            constexpr int NV = 64 * FI / 4;
#pragma unroll
            for (int idx = t; idx < NV; idx += 256) {
                int r = idx / (FI / 4), c = idx % (FI / 4);
                float4 v = make_float4(0.f, 0.f, 0.f, 0.f);
                if (n_base + r < N_NODES) v = s4[idx];
                *(float4*)(Ts + r * TS + 4 * c) = v;
            }
            const float4* w4 = (const float4*)(W + (size_t)k * FI * FO);
            constexpr int WV = FI * FO / 4;
#pragma unroll
            for (int idx = t; idx < WV; idx += 256) *(float4*)(Ws + 4 * idx) = w4[idx];
        }
        __syncthreads();
#pragma unroll
        for (int f0 = 0; f0 < FI; f0 += 4) {
            float tv[4][4];
#pragma unroll
            for (int i = 0; i < 4; ++i) {
                float4 q = *(const float4*)(Ts + (tn + 16 * i) * TS + f0);
                tv[i][0] = q.x; tv[i][1] = q.y; tv[i][2] = q.z; tv[i][3] = q.w;
            }
#pragma unroll
            for (int j = 0; j < 4; ++j) {
                float4 w = *(const float4*)(Ws + (f0 + j) * FO + 4 * to);
#pragma unroll
                for (int i = 0; i < 4; ++i) {
                    acc[i][0] = fmaf(tv[i][j], w.x, acc[i][0]);
                    acc[i][1] = fmaf(tv[i][j], w.y, acc[i][1]);
                    acc[i][2] = fmaf(tv[i][j], w.z, acc[i][2]);
                    acc[i][3] = fmaf(tv[i][j], w.w, acc[i][3]);
                }
            }
        }
    }
    __syncthreads();
#pragma unroll
    for (int i = 0; i < 4; ++i) {
        int n = n_base + tn + 16 * i;
        if (n < N_NODES) {
            float4 r = make_float4(fmaxf(acc[i][0], 0.f), fmaxf(acc[i][1], 0.f),
                                   fmaxf(acc[i][2], 0.f), fmaxf(acc[i][3], 0.f));
            *(float4*)(out + (size_t)n * FO + 4 * to) = r;
        }
    }
}

__global__ void combine432_kernel(const float* __restrict__ X, const float* __restrict__ T1,
                                  const float* __restrict__ T2, const float* __restrict__ T3,
                                  const float* __restrict__ T4, const float* __restrict__ W,
                                  const float* __restrict__ b, float* __restrict__ out) {
    __shared__ float Ws[5 * 4 * 32];
    int t = threadIdx.x;
    for (int i = t; i < 5 * 4 * 32; i += 256) Ws[i] = W[i];
    __syncthreads();
    int node = blockIdx.x * 8 + (t >> 5);
    int o = t & 31;
    if (node >= N_NODES) return;
    const float4* Tk[5] = {(const float4*)X, (const float4*)T1, (const float4*)T2,
                           (const float4*)T3, (const float4*)T4};
    float acc = b[o];
#pragma unroll
    for (int k = 0; k < 5; ++k) {
        float4 q = Tk[k][node];
        const float* w = Ws + k * 128 + o;
        acc = fmaf(q.x, w[0], acc);
        acc = fmaf(q.y, w[32], acc);
        acc = fmaf(q.z, w[64], acc);
        acc = fmaf(q.w, w[96], acc);
    }
    out[(size_t)node * 32 + o] = fmaxf(acc, 0.f);
}

// ---- pooling + MLP -----------------------------------------------------

__global__ void pool_kernel(const float* __restrict__ h, const int* __restrict__ batch,
                            float* __restrict__ pooled, float* __restrict__ cntf) {
    int wid = blockIdx.x * (blockDim.x / 64) + (threadIdx.x >> 6);
    int lane = threadIdx.x & 63;
    int nwaves = gridDim.x * (blockDim.x / 64);
    int per = (N_NODES + nwaves - 1) / nwaves;
    int n0 = wid * per;
    int n1 = min(n0 + per, N_NODES);
    if (n0 >= n1) return;
    int cur = batch[n0];
    float acc = 0.f;
    int c = 0;
    for (int n = n0; n < n1; ++n) {
        int g = batch[n];
        if (g != cur) {
            atomicAdd(&pooled[cur * 64 + lane], acc);
            if (lane == 0) atomicAdd(&cntf[cur], (float)c);
            acc = 0.f; c = 0; cur = g;
        }
        acc += h[(size_t)n * 64 + lane];
        ++c;
    }
    atomicAdd(&pooled[cur * 64 + lane], acc);
    if (lane == 0) atomicAdd(&cntf[cur], (float)c);
}

__global__ void fc_kernel(const float* __restrict__ pooled, const float* __restrict__ cnt,
                          const float* __restrict__ w1, const float* __restrict__ b1,
                          const float* __restrict__ w2, const float* __restrict__ b2,
                          float* __restrict__ out) {
    int g = blockIdx.x;
    int t = threadIdx.x;
    __shared__ float hid[32];
    float c = fmaxf(cnt[g], 1.0f);
    float acc = b1[t];
    for (int f = 0; f < 64; ++f) acc = fmaf(pooled[g * 64 + f] / c, w1[f * 32 + t], acc);
    hid[t] = fmaxf(acc, 0.f);
    __syncthreads();
    if (t == 0) {
        float acc2 = b2[0];
        for (int o = 0; o < 32; ++o) acc2 = fmaf(hid[o], w2[o], acc2);
        out[g] = acc2;
    }
}

// ---- host orchestration ------------------------------------------------

template <int FI, int FO>
static void run_layer(const int* row, const float2* csr, const float* X,
                      float* T1, float* T2, float* T3, float* T4,
                      const float* W, const float* b, float* out, hipStream_t stream) {
    if constexpr (FI == 4) {
        dim3 g(cdiv(N_NODES, 256)), blk(256);
        hipLaunchKernelGGL(gather4_kernel, g, blk, 0, stream, row, csr, X,  X,  T1, 1.f, 0.f);
        hipLaunchKernelGGL(gather4_kernel, g, blk, 0, stream, row, csr, T1, X,  T2, 2.f, -1.f);
        hipLaunchKernelGGL(gather4_kernel, g, blk, 0, stream, row, csr, T2, T1, T3, 2.f, -1.f);
        hipLaunchKernelGGL(gather4_kernel, g, blk, 0, stream, row, csr, T3, T2, T4, 2.f, -1.f);
    } else {
        constexpr int NPB = 256 / FI;
        dim3 g(cdiv(N_NODES, NPB)), blk(256);
        hipLaunchKernelGGL((gather_kernel<FI>), g, blk, 0, stream, row, csr, X,  X,  T1, 1.f, 0.f);
        hipLaunchKernelGGL((gather_kernel<FI>), g, blk, 0, stream, row, csr, T1, X,  T2, 2.f, -1.f);
        hipLaunchKernelGGL((gather_kernel<FI>), g, blk, 0, stream, row, csr, T2, T1, T3, 2.f, -1.f);
        hipLaunchKernelGGL((gather_kernel<FI>), g, blk, 0, stream, row, csr, T3, T2, T4, 2.f, -1.f);
    }
    if constexpr (FO == 64) {
        hipLaunchKernelGGL((combine64_kernel<FI>), dim3(cdiv(N_NODES, 64)), dim3(256), 0,
                           stream, X, T1, T2, T3, T4, W, b, out);
    } else {
        hipLaunchKernelGGL(combine432_kernel, dim3(cdiv(N_NODES, 8)), dim3(256), 0,
                           stream, X, T1, T2, T3, T4, W, b, out);
    }
}

extern "C" void kernel_launch(void* const* d_in, const int* in_sizes, int n_in,
                              void* d_out, int out_size, void* d_ws, size_t ws_size,
                              hipStream_t stream) {
    const float* x    = (const float*)d_in[0];
    const int*   ei   = (const int*)d_in[1];
    const int*   batch= (const int*)d_in[2];
    const float* W1   = (const float*)d_in[4];
    const float* b1   = (const float*)d_in[5];
    const float* W2   = (const float*)d_in[6];
    const float* b2   = (const float*)d_in[7];
    const float* W3   = (const float*)d_in[8];
    const float* b3   = (const float*)d_in[9];
    const float* fcw1 = (const float*)d_in[10];
    const float* fcb1 = (const float*)d_in[11];
    const float* fcw2 = (const float*)d_in[12];
    const float* fcb2 = (const float*)d_in[13];

    const int* src = ei;
    const int* dst = ei + N_EDGES;

    float* base = (float*)d_ws;
    float*  dinv   = base + 0;                      // 50000
    int*    cnt_i  = (int*)(base + 50000);          // 50000
    int*    row    = (int*)(base + 100000);         // 50004
    int*    bsum   = (int*)(base + 150004);         // 252
    float2* csr    = (float2*)(base + 150256);      // 1.6M float2 = 3.2M floats
    float*  T1     = base + 3350256;                // 3.2M each
    float*  T2     = base + 6550256;
    float*  T3     = base + 9750256;
    float*  T4     = base + 12950256;
    float*  H1     = T4 + 1600000;                  // layer1 out (F=32), T4 top half
    float*  H2     = base + 16150256;
    float*  pooled = base + 19350256;
    float*  cntf   = base + 19358448;

    // build-phase scratch aliases T1..T3 (dead until gathers start)
    unsigned* Hs = (unsigned*)T1;  // 256*12500 u32 = 12.8 MB
    unsigned* Hd = (unsigned*)T2;
    unsigned* P  = (unsigned*)T3;

    hipLaunchKernelGGL((hist_kernel<0>), dim3(NB_H), dim3(256), 0, stream, src, dst, Hs);
    hipLaunchKernelGGL((hist_kernel<1>), dim3(NB_H), dim3(256), 0, stream, src, dst, Hd);
    hipLaunchKernelGGL(merge_src_kernel, dim3(cdiv(NW, 256)), dim3(256), 0, stream, Hs, dinv);
    hipLaunchKernelGGL(merge_dst_kernel, dim3(cdiv(NW, 256)), dim3(256), 0, stream, Hd, P, cnt_i);
    hipLaunchKernelGGL(scan_block_kernel, dim3(SCAN_NB), dim3(SCAN_B), 0, stream, cnt_i, row, bsum);
    hipLaunchKernelGGL(scan_sums_kernel, dim3(1), dim3(256), 0, stream, bsum);
    hipLaunchKernelGGL(scan_add_kernel, dim3(SCAN_NB), dim3(SCAN_B), 0, stream, row, bsum);
    hipLaunchKernelGGL(place_kernel, dim3(NB_H), dim3(256), 0, stream,
                       src, dst, dinv, row, P, csr);

    run_layer<4, 32>(row, csr, x,  T1, T2, T3, T4, W1, b1, H1, stream);
    run_layer<32, 64>(row, csr, H1, T1, T2, T3, T4, W2, b2, H2, stream);
    run_layer<64, 64>(row, csr, H2, T1, T2, T3, T4, W3, b3, T1, stream);

    hipMemsetAsync(pooled, 0, (8192 + 128) * sizeof(float), stream);
    hipLaunchKernelGGL(pool_kernel, dim3(128), dim3(256), 0, stream, T1, batch, pooled, cntf);
    hipLaunchKernelGGL(fc_kernel, dim3(N_GRAPHS), dim3(32), 0, stream,
                       pooled, cntf, fcw1, fcb1, fcw2, fcb2, (float*)d_out);
}

// Round 5
// 808.568 us; speedup vs baseline: 4.2151x; 1.1185x over previous
//
#include <hip/hip_runtime.h>

// ChebNet on MI355X — Round 5: fix combine64 occupancy (VGPR 256 -> <=128 via
// __launch_bounds__(256,4) + bounded f0 unroll). Rest unchanged from R4.

constexpr int N_NODES  = 50000;
constexpr int N_EDGES  = 1600000;
constexpr int N_GRAPHS = 128;

constexpr int NB_H = 256;                 // histogram/place blocks
constexpr int EPB  = N_EDGES / NB_H;      // 6250 edges per block (exact)
constexpr int NW   = (N_NODES + 3) / 4;   // 12500 packed words (4 u8 bins each)

static inline int cdiv(long long a, int b) { return (int)((a + b - 1) / b); }

// ---- CSR build (atomic-free at device scope) ---------------------------

template <int USE_DST>
__global__ __launch_bounds__(256) void hist_kernel(const int* __restrict__ src,
                                                   const int* __restrict__ dst,
                                                   unsigned* __restrict__ H) {
    __shared__ unsigned lds[NW];  // 50 KB: 4 byte-bins per word
    const int b = blockIdx.x, t = threadIdx.x;
    for (int i = t; i < NW; i += 256) lds[i] = 0;
    __syncthreads();
    const int e0 = b * EPB, e1 = e0 + EPB;
    for (int e = e0 + t; e < e1; e += 256) {
        int s = src[e], d = dst[e];
        if (s != d) {
            int key = USE_DST ? d : s;
            atomicAdd(&lds[key >> 2], 1u << (8 * (key & 3)));
        }
    }
    __syncthreads();
    unsigned* Hb = H + (size_t)b * NW;
    for (int i = t; i < NW; i += 256) Hb[i] = lds[i];
}

__global__ void merge_src_kernel(const unsigned* __restrict__ H, float* __restrict__ dinv) {
    int i = blockIdx.x * blockDim.x + threadIdx.x;
    if (i >= NW) return;
    unsigned s0 = 0, s1 = 0, s2 = 0, s3 = 0;
    for (int b = 0; b < NB_H; ++b) {
        unsigned v = H[(size_t)b * NW + i];
        s0 += v & 0xff; s1 += (v >> 8) & 0xff; s2 += (v >> 16) & 0xff; s3 += v >> 24;
    }
    dinv[4 * i + 0] = s0 ? rsqrtf((float)s0) : 0.f;
    dinv[4 * i + 1] = s1 ? rsqrtf((float)s1) : 0.f;
    dinv[4 * i + 2] = s2 ? rsqrtf((float)s2) : 0.f;
    dinv[4 * i + 3] = s3 ? rsqrtf((float)s3) : 0.f;
}

__global__ void merge_dst_kernel(const unsigned* __restrict__ H, unsigned* __restrict__ P,
                                 int* __restrict__ cnt) {
    int i = blockIdx.x * blockDim.x + threadIdx.x;
    if (i >= NW) return;
    unsigned p0 = 0, p1 = 0, p2 = 0, p3 = 0;
    for (int b = 0; b < NB_H; ++b) {
        size_t idx = (size_t)b * NW + i;
        unsigned v = H[idx];
        P[idx] = p0 | (p1 << 8) | (p2 << 16) | (p3 << 24);
        p0 += v & 0xff; p1 += (v >> 8) & 0xff; p2 += (v >> 16) & 0xff; p3 += v >> 24;
    }
    cnt[4 * i + 0] = (int)p0; cnt[4 * i + 1] = (int)p1;
    cnt[4 * i + 2] = (int)p2; cnt[4 * i + 3] = (int)p3;
}

// ---- 3-phase scan ------------------------------------------------------

constexpr int SCAN_B = 256;
constexpr int SCAN_NB = (N_NODES + SCAN_B - 1) / SCAN_B;  // 196

__global__ void scan_block_kernel(const int* __restrict__ cnt, int* __restrict__ row,
                                  int* __restrict__ bsum) {
    __shared__ int buf[SCAN_B];
    int t = threadIdx.x;
    int i = blockIdx.x * SCAN_B + t;
    buf[t] = (i < N_NODES) ? cnt[i] : 0;
    __syncthreads();
    for (int off = 1; off < SCAN_B; off <<= 1) {
        int a = (t >= off) ? buf[t - off] : 0;
        __syncthreads();
        buf[t] += a;
        __syncthreads();
    }
    if (i < N_NODES) row[i + 1] = buf[t];
    if (t == SCAN_B - 1) bsum[blockIdx.x] = buf[t];
    if (i == 0) row[0] = 0;
}

__global__ void scan_sums_kernel(int* __restrict__ bsum) {
    __shared__ int buf[SCAN_NB];
    int t = threadIdx.x;
    if (t < SCAN_NB) buf[t] = bsum[t];
    __syncthreads();
    for (int off = 1; off < SCAN_NB; off <<= 1) {
        int a = (t >= off && t < SCAN_NB) ? buf[t - off] : 0;
        __syncthreads();
        if (t < SCAN_NB) buf[t] += a;
        __syncthreads();
    }
    if (t < SCAN_NB) bsum[t] = buf[t];
}

__global__ void scan_add_kernel(int* __restrict__ row, const int* __restrict__ bsum) {
    int i = blockIdx.x * SCAN_B + threadIdx.x;
    if (blockIdx.x > 0 && i < N_NODES) row[i + 1] += bsum[blockIdx.x - 1];
}

__global__ __launch_bounds__(256) void place_kernel(const int* __restrict__ src,
                                                    const int* __restrict__ dst,
                                                    const float* __restrict__ dinv,
                                                    const int* __restrict__ row,
                                                    const unsigned* __restrict__ P,
                                                    float2* __restrict__ csr) {
    __shared__ unsigned lds[NW];
    const int b = blockIdx.x, t = threadIdx.x;
    for (int i = t; i < NW; i += 256) lds[i] = 0;
    __syncthreads();
    const int e0 = b * EPB, e1 = e0 + EPB;
    const unsigned* Pb = P + (size_t)b * NW;
    for (int e = e0 + t; e < e1; e += 256) {
        int s = src[e], d = dst[e];
        if (s != d) {
            float w = -dinv[s] * dinv[d];
            int sh = 8 * (d & 3);
            unsigned old = atomicAdd(&lds[d >> 2], 1u << sh);
            unsigned cur = (old >> sh) & 0xff;
            unsigned pref = (Pb[d >> 2] >> sh) & 0xff;
            int pos = row[d] + (int)pref + (int)cur;
            csr[pos] = make_float2(w, __int_as_float(s));
        }
    }
}

// ---- L(z) gathers ------------------------------------------------------

template <int F>
__global__ void gather_kernel(const int* __restrict__ row, const float2* __restrict__ csr,
                              const float* __restrict__ z, const float* __restrict__ prev,
                              float* __restrict__ out, float alpha, float beta) {
    constexpr int NPB = 256 / F;
    int node = blockIdx.x * NPB + threadIdx.x / F;
    int lane = threadIdx.x % F;
    if (node >= N_NODES) return;
    int e0 = row[node], e1 = row[node + 1];
    float acc = 0.f;
#pragma unroll 4
    for (int e = e0; e < e1; ++e) {
        float2 ew = csr[e];
        acc = fmaf(ew.x, z[(size_t)__float_as_int(ew.y) * F + lane], acc);
    }
    float r = alpha * acc;
    if (beta != 0.f) r = fmaf(beta, prev[(size_t)node * F + lane], r);
    out[(size_t)node * F + lane] = r;
}

__global__ void gather4_kernel(const int* __restrict__ row, const float2* __restrict__ csr,
                               const float* __restrict__ z, const float* __restrict__ prev,
                               float* __restrict__ out, float alpha, float beta) {
    int node = blockIdx.x * blockDim.x + threadIdx.x;
    if (node >= N_NODES) return;
    int e0 = row[node], e1 = row[node + 1];
    const float4* z4 = (const float4*)z;
    float4 a = make_float4(0.f, 0.f, 0.f, 0.f);
#pragma unroll 4
    for (int e = e0; e < e1; ++e) {
        float2 ew = csr[e];
        float4 zz = z4[__float_as_int(ew.y)];
        a.x = fmaf(ew.x, zz.x, a.x);
        a.y = fmaf(ew.x, zz.y, a.y);
        a.z = fmaf(ew.x, zz.z, a.z);
        a.w = fmaf(ew.x, zz.w, a.w);
    }
    float4 r = make_float4(alpha * a.x, alpha * a.y, alpha * a.z, alpha * a.w);
    if (beta != 0.f) {
        const float4 p = ((const float4*)prev)[node];
        r.x = fmaf(beta, p.x, r.x);
        r.y = fmaf(beta, p.y, r.y);
        r.z = fmaf(beta, p.z, r.z);
        r.w = fmaf(beta, p.w, r.w);
    }
    ((float4*)out)[node] = r;
}

// ---- combine: out[n,o] = relu(b[o] + sum_k T_k[n,:] @ W[k,:,o]) --------
// 64-node x 64-out tile, 4x4 reg tile. __launch_bounds__(256,4): cap VGPR
// at 128 so 4 blocks/CU (16 waves) co-reside; LDS 33KB*4 = 132KB fits.
// f0 unroll limited to 4 to stop ds_read hoisting from blowing registers.

template <int FI>
__global__ __launch_bounds__(256, 4) void combine64_kernel(
        const float* __restrict__ X, const float* __restrict__ T1,
        const float* __restrict__ T2, const float* __restrict__ T3,
        const float* __restrict__ T4, const float* __restrict__ W,
        const float* __restrict__ b, float* __restrict__ out) {
    constexpr int FO = 64;
    constexpr int TS = FI + 4;
    __shared__ float Ts[64 * TS];
    __shared__ float Ws[FI * FO];
    const int t = threadIdx.x;
    const int tn = t & 15;
    const int to = t >> 4;
    const int n_base = blockIdx.x * 64;
    const float* Tk[5] = {X, T1, T2, T3, T4};

    float acc[4][4];
    {
        const float4 bb = *(const float4*)(b + 4 * to);
#pragma unroll
        for (int i = 0; i < 4; ++i) {
            acc[i][0] = bb.x; acc[i][1] = bb.y; acc[i][2] = bb.z; acc[i][3] = bb.w;
        }
    }

#pragma unroll
    for (int k = 0; k < 5; ++k) {
        __syncthreads();
        {
            const float4* s4 = (const float4*)(Tk[k] + (size_t)n_base * FI);
            constexpr int NV = 64 * FI / 4;
#pragma unroll
            for (int idx = t; idx < NV; idx += 256) {
                int r = idx / (FI / 4), c = idx % (FI / 4);
                float4 v = make_float4(0.f, 0.f, 0.f, 0.f);
                if (n_base + r < N_NODES) v = s4[idx];
                *(float4*)(Ts + r * TS + 4 * c) = v;
            }
            const float4* w4 = (const float4*)(W + (size_t)k * FI * FO);
            constexpr int WV = FI * FO / 4;
#pragma unroll
            for (int idx = t; idx < WV; idx += 256) *(float4*)(Ws + 4 * idx) = w4[idx];
        }
        __syncthreads();
#pragma unroll 4
        for (int f0 = 0; f0 < FI; f0 += 4) {
            float tv[4][4];
#pragma unroll
            for (int i = 0; i < 4; ++i) {
                float4 q = *(const float4*)(Ts + (tn + 16 * i) * TS + f0);
                tv[i][0] = q.x; tv[i][1] = q.y; tv[i][2] = q.z; tv[i][3] = q.w;
            }
#pragma unroll
            for (int j = 0; j < 4; ++j) {
                float4 w = *(const float4*)(Ws + (f0 + j) * FO + 4 * to);
#pragma unroll
                for (int i = 0; i < 4; ++i) {
                    acc[i][0] = fmaf(tv[i][j], w.x, acc[i][0]);
                    acc[i][1] = fmaf(tv[i][j], w.y, acc[i][1]);
                    acc[i][2] = fmaf(tv[i][j], w.z, acc[i][2]);
                    acc[i][3] = fmaf(tv[i][j], w.w, acc[i][3]);
                }
            }
        }
    }
    __syncthreads();
#pragma unroll
    for (int i = 0; i < 4; ++i) {
        int n = n_base + tn + 16 * i;
        if (n < N_NODES) {
            float4 r = make_float4(fmaxf(acc[i][0], 0.f), fmaxf(acc[i][1], 0.f),
                                   fmaxf(acc[i][2], 0.f), fmaxf(acc[i][3], 0.f));
            *(float4*)(out + (size_t)n * FO + 4 * to) = r;
        }
    }
}

__global__ void combine432_kernel(const float* __restrict__ X, const float* __restrict__ T1,
                                  const float* __restrict__ T2, const float* __restrict__ T3,
                                  const float* __restrict__ T4, const float* __restrict__ W,
                                  const float* __restrict__ b, float* __restrict__ out) {
    __shared__ float Ws[5 * 4 * 32];
    int t = threadIdx.x;
    for (int i = t; i < 5 * 4 * 32; i += 256) Ws[i] = W[i];
    __syncthreads();
    int node = blockIdx.x * 8 + (t >> 5);
    int o = t & 31;
    if (node >= N_NODES) return;
    const float4* Tk[5] = {(const float4*)X, (const float4*)T1, (const float4*)T2,
                           (const float4*)T3, (const float4*)T4};
    float acc = b[o];
#pragma unroll
    for (int k = 0; k < 5; ++k) {
        float4 q = Tk[k][node];
        const float* w = Ws + k * 128 + o;
        acc = fmaf(q.x, w[0], acc);
        acc = fmaf(q.y, w[32], acc);
        acc = fmaf(q.z, w[64], acc);
        acc = fmaf(q.w, w[96], acc);
    }
    out[(size_t)node * 32 + o] = fmaxf(acc, 0.f);
}

// ---- pooling + MLP -----------------------------------------------------

__global__ void pool_kernel(const float* __restrict__ h, const int* __restrict__ batch,
                            float* __restrict__ pooled, float* __restrict__ cntf) {
    int wid = blockIdx.x * (blockDim.x / 64) + (threadIdx.x >> 6);
    int lane = threadIdx.x & 63;
    int nwaves = gridDim.x * (blockDim.x / 64);
    int per = (N_NODES + nwaves - 1) / nwaves;
    int n0 = wid * per;
    int n1 = min(n0 + per, N_NODES);
    if (n0 >= n1) return;
    int cur = batch[n0];
    float acc = 0.f;
    int c = 0;
    for (int n = n0; n < n1; ++n) {
        int g = batch[n];
        if (g != cur) {
            atomicAdd(&pooled[cur * 64 + lane], acc);
            if (lane == 0) atomicAdd(&cntf[cur], (float)c);
            acc = 0.f; c = 0; cur = g;
        }
        acc += h[(size_t)n * 64 + lane];
        ++c;
    }
    atomicAdd(&pooled[cur * 64 + lane], acc);
    if (lane == 0) atomicAdd(&cntf[cur], (float)c);
}

__global__ void fc_kernel(const float* __restrict__ pooled, const float* __restrict__ cnt,
                          const float* __restrict__ w1, const float* __restrict__ b1,
                          const float* __restrict__ w2, const float* __restrict__ b2,
                          float* __restrict__ out) {
    int g = blockIdx.x;
    int t = threadIdx.x;
    __shared__ float hid[32];
    float c = fmaxf(cnt[g], 1.0f);
    float acc = b1[t];
    for (int f = 0; f < 64; ++f) acc = fmaf(pooled[g * 64 + f] / c, w1[f * 32 + t], acc);
    hid[t] = fmaxf(acc, 0.f);
    __syncthreads();
    if (t == 0) {
        float acc2 = b2[0];
        for (int o = 0; o < 32; ++o) acc2 = fmaf(hid[o], w2[o], acc2);
        out[g] = acc2;
    }
}

// ---- host orchestration ------------------------------------------------

template <int FI, int FO>
static void run_layer(const int* row, const float2* csr, const float* X,
                      float* T1, float* T2, float* T3, float* T4,
                      const float* W, const float* b, float* out, hipStream_t stream) {
    if constexpr (FI == 4) {
        dim3 g(cdiv(N_NODES, 256)), blk(256);
        hipLaunchKernelGGL(gather4_kernel, g, blk, 0, stream, row, csr, X,  X,  T1, 1.f, 0.f);
        hipLaunchKernelGGL(gather4_kernel, g, blk, 0, stream, row, csr, T1, X,  T2, 2.f, -1.f);
        hipLaunchKernelGGL(gather4_kernel, g, blk, 0, stream, row, csr, T2, T1, T3, 2.f, -1.f);
        hipLaunchKernelGGL(gather4_kernel, g, blk, 0, stream, row, csr, T3, T2, T4, 2.f, -1.f);
    } else {
        constexpr int NPB = 256 / FI;
        dim3 g(cdiv(N_NODES, NPB)), blk(256);
        hipLaunchKernelGGL((gather_kernel<FI>), g, blk, 0, stream, row, csr, X,  X,  T1, 1.f, 0.f);
        hipLaunchKernelGGL((gather_kernel<FI>), g, blk, 0, stream, row, csr, T1, X,  T2, 2.f, -1.f);
        hipLaunchKernelGGL((gather_kernel<FI>), g, blk, 0, stream, row, csr, T2, T1, T3, 2.f, -1.f);
        hipLaunchKernelGGL((gather_kernel<FI>), g, blk, 0, stream, row, csr, T3, T2, T4, 2.f, -1.f);
    }
    if constexpr (FO == 64) {
        hipLaunchKernelGGL((combine64_kernel<FI>), dim3(cdiv(N_NODES, 64)), dim3(256), 0,
                           stream, X, T1, T2, T3, T4, W, b, out);
    } else {
        hipLaunchKernelGGL(combine432_kernel, dim3(cdiv(N_NODES, 8)), dim3(256), 0,
                           stream, X, T1, T2, T3, T4, W, b, out);
    }
}

extern "C" void kernel_launch(void* const* d_in, const int* in_sizes, int n_in,
                              void* d_out, int out_size, void* d_ws, size_t ws_size,
                              hipStream_t stream) {
    const float* x    = (const float*)d_in[0];
    const int*   ei   = (const int*)d_in[1];
    const int*   batch= (const int*)d_in[2];
    const float* W1   = (const float*)d_in[4];
    const float* b1   = (const float*)d_in[5];
    const float* W2   = (const float*)d_in[6];
    const float* b2   = (const float*)d_in[7];
    const float* W3   = (const float*)d_in[8];
    const float* b3   = (const float*)d_in[9];
    const float* fcw1 = (const float*)d_in[10];
    const float* fcb1 = (const float*)d_in[11];
    const float* fcw2 = (const float*)d_in[12];
    const float* fcb2 = (const float*)d_in[13];

    const int* src = ei;
    const int* dst = ei + N_EDGES;

    float* base = (float*)d_ws;
    float*  dinv   = base + 0;                      // 50000
    int*    cnt_i  = (int*)(base + 50000);          // 50000
    int*    row    = (int*)(base + 100000);         // 50004
    int*    bsum   = (int*)(base + 150004);         // 252
    float2* csr    = (float2*)(base + 150256);      // 1.6M float2
    float*  T1     = base + 3350256;
    float*  T2     = base + 6550256;
    float*  T3     = base + 9750256;
    float*  T4     = base + 12950256;
    float*  H1     = T4 + 1600000;                  // layer1 out (F=32), T4 top half
    float*  H2     = base + 16150256;
    float*  pooled = base + 19350256;
    float*  cntf   = base + 19358448;

    unsigned* Hs = (unsigned*)T1;  // build-phase scratch aliases T1..T3
    unsigned* Hd = (unsigned*)T2;
    unsigned* P  = (unsigned*)T3;

    hipLaunchKernelGGL((hist_kernel<0>), dim3(NB_H), dim3(256), 0, stream, src, dst, Hs);
    hipLaunchKernelGGL((hist_kernel<1>), dim3(NB_H), dim3(256), 0, stream, src, dst, Hd);
    hipLaunchKernelGGL(merge_src_kernel, dim3(cdiv(NW, 256)), dim3(256), 0, stream, Hs, dinv);
    hipLaunchKernelGGL(merge_dst_kernel, dim3(cdiv(NW, 256)), dim3(256), 0, stream, Hd, P, cnt_i);
    hipLaunchKernelGGL(scan_block_kernel, dim3(SCAN_NB), dim3(SCAN_B), 0, stream, cnt_i, row, bsum);
    hipLaunchKernelGGL(scan_sums_kernel, dim3(1), dim3(256), 0, stream, bsum);
    hipLaunchKernelGGL(scan_add_kernel, dim3(SCAN_NB), dim3(SCAN_B), 0, stream, row, bsum);
    hipLaunchKernelGGL(place_kernel, dim3(NB_H), dim3(256), 0, stream,
                       src, dst, dinv, row, P, csr);

    run_layer<4, 32>(row, csr, x,  T1, T2, T3, T4, W1, b1, H1, stream);
    run_layer<32, 64>(row, csr, H1, T1, T2, T3, T4, W2, b2, H2, stream);
    run_layer<64, 64>(row, csr, H2, T1, T2, T3, T4, W3, b3, T1, stream);

    hipMemsetAsync(pooled, 0, (8192 + 128) * sizeof(float), stream);
    hipLaunchKernelGGL(pool_kernel, dim3(128), dim3(256), 0, stream, T1, batch, pooled, cntf);
    hipLaunchKernelGGL(fc_kernel, dim3(N_GRAPHS), dim3(32), 0, stream,
                       pooled, cntf, fcw1, fcb1, fcw2, fcb2, (float*)d_out);
}